// Round 6
// baseline (4771.613 us; speedup 1.0000x reference)
//
#include <hip/hip_runtime.h>
#include <cmath>

// VQ-VAE quantization forward: B=64, K=1024, D=128, H=W=32.
// Ref model (6 rounds of absmax triangulation): q_k = fl32(fl32(A - fl32(2*B_k)) + C_k),
// first-index argmin, B = single-accumulator SEQUENTIAL FMA over d.
// A = sum(z*z,-1) sequential; C = sum(emb*emb,-1) pairwise-8.
// out0 = fl(fl(e-z)+z); out1 = e. Exact chains pinned with empty-asm barriers.
//
// R6: R4/R5 proved the MFMA-coarse + exact-refinement architecture (absmax 0)
// but both stalled ~98% on the d_ws global e-table feed (VGPR=52 => zero tiles
// in flight; R5's coalescing changed NOTHING => the serialized VMEM dependency,
// not the access pattern, was the pit). Replace the feed entirely:
//  * NO workspace table. Per block, e-tiles are cooperatively staged into a
//    double-buffered LDS fragment buffer, converting fp32->bf16 on the fly
//    (identical f2bf bits => coarse scores bitwise-identical to R4/R5).
//  * 4 tiles (64 codes) per round, 16 rounds per pass, ONE barrier per round;
//    staging of round r+1 overlaps MFMA of round r (R3's proven dbuf pattern).
//  * Every ds_read_b128 delivers 16B of unique per-lane fragment payload
//    (R3's broadcast amplification is gone); LDS-pipe model ~23us/block.
// Unchanged from the PASSING R4/R5: fragment bijection (l&15=code, l>>4=d-slice),
// C/D map col=lane&15(code) row=(lane>>4)*4+reg(px), pass1 min -> shfl reduce ->
// pass2 bitwise-identical recompute + window collect (TH=4e-3, CAP=16,
// full-scan fallback), exact pinned snorm/A/B/epilogue chains, first-index
// tie-break.

#define D_DIM   128
#define K_CODES 1024
#define HW_SZ   1024
#define N_PIX   65536
#define OUT_OFF ((size_t)N_PIX * D_DIM)

#define PXB     128                     // pixels per block
#define NW      8                       // waves per block
#define NTILE   (K_CODES / 16)          // 64 code-tiles
#define TPR     4                       // tiles staged per round
#define ROUNDS  (NTILE / TPR)           // 16
#define ZLD     132                     // padded z row (floats)
#define TH      4.0e-3f                 // coarse candidate window
#define CAP     16                      // worklist capacity per pixel

typedef float  f32x4 __attribute__((ext_vector_type(4)));
typedef short  s16x8 __attribute__((ext_vector_type(8)));
typedef unsigned short u16x8 __attribute__((ext_vector_type(8)));

// --- compiler-proof fp32 ops: result pinned in a VGPR via empty asm ---
__device__ __forceinline__ float fmul_x(float a, float b) {
    float r = a * b; asm volatile("" : "+v"(r)); return r;
}
__device__ __forceinline__ float fadd_x(float a, float b) {
    float r = a + b; asm volatile("" : "+v"(r)); return r;
}
__device__ __forceinline__ float fsub_x(float a, float b) {
    float r = a - b; asm volatile("" : "+v"(r)); return r;
}
__device__ __forceinline__ float ffma_x(float a, float b, float c) {
    float r = fmaf(a, b, c); asm volatile("" : "+v"(r)); return r;
}

// RNE float -> bf16 bits (inputs are normal floats here)
__device__ __forceinline__ unsigned short f2bf(float f) {
    unsigned u = __float_as_uint(f);
    u += 0x7FFFu + ((u >> 16) & 1u);
    return (unsigned short)(u >> 16);
}

// Stage TPR tiles (Tbase..Tbase+3) into dst in fragment order:
// dst[((tt*4 + dt)*64 + l)*8 + j] = bf16(emb[(Tbase+tt)*16 + (l&15)][dt*32 + ((l>>4)&3)*8 + j])
__device__ __forceinline__ void stage_tiles(
    const float* __restrict__ emb, unsigned short* __restrict__ dst,
    const int Tbase, const int tid)
{
    #pragma unroll
    for (int h = 0; h < 2; ++h) {
        const int f  = h * 512 + tid;        // fragment id 0..1023
        const int tt = f >> 8;               // tile within round
        const int dt = (f >> 6) & 3;         // d-block
        const int l  = f & 63;               // fragment lane
        const int code = (Tbase + tt) * 16 + (l & 15);
        const int d0   = dt * 32 + ((l >> 4) & 3) * 8;
        const float* src = emb + (size_t)code * D_DIM + d0;
        const f32x4 a = *(const f32x4*)(src);
        const f32x4 b = *(const f32x4*)(src + 4);
        u16x8 o;
        o[0] = f2bf(a[0]); o[1] = f2bf(a[1]); o[2] = f2bf(a[2]); o[3] = f2bf(a[3]);
        o[4] = f2bf(b[0]); o[5] = f2bf(b[1]); o[6] = f2bf(b[2]); o[7] = f2bf(b[3]);
        *(u16x8*)(dst + (size_t)f * 8) = o;
    }
}

__global__ __launch_bounds__(512, 2) void vq_fused(
    const float* __restrict__ z_e,
    const float* __restrict__ emb,
    float* __restrict__ out)
{
#pragma clang fp contract(off)
    __shared__ float s_zT[PXB][ZLD];                        // 66 KB fp32 z, [px][d]
    __shared__ alignas(16) unsigned short e_s[2][TPR * 2048]; // 2 x 16 KB frag buffers
    __shared__ float snorm[K_CODES];                        // 4 KB
    __shared__ int   s_cnt[PXB];                            // worklist counters
    __shared__ int   s_ck[PXB][CAP];                        // 8 KB worklist codes
    __shared__ int   s_kwin[PXB];

    const int px  = threadIdx.x;                // lane 0..63
    const int ky  = threadIdx.y;                // wave 0..7
    const int tid = ky * 64 + px;

    const int p0  = blockIdx.x * PXB;
    const int b   = p0 >> 10;
    const int hw0 = p0 & (HW_SZ - 1);
    const float* zbase = z_e + (size_t)b * (D_DIM * HW_SZ) + hw0;

    if (tid < PXB) s_cnt[tid] = 0;

    // ---- z stage: global [d][128 px] -> s_zT[px][d] (transpose) ----
    #pragma unroll
    for (int r = 0; r < 8; ++r) {
        const int idx = r * 512 + tid;          // 0..4095
        const int d   = idx >> 5;               // 0..127
        const int i4  = (idx & 31) * 4;         // pixel group
        const f32x4 v = *(const f32x4*)(zbase + (size_t)d * HW_SZ + i4);
        s_zT[i4 + 0][d] = v[0];
        s_zT[i4 + 1][d] = v[1];
        s_zT[i4 + 2][d] = v[2];
        s_zT[i4 + 3][d] = v[3];
    }

    // ---- C_k = np.sum(emb*emb,-1): pairwise-8 (n=128), chain verbatim ----
    for (int k = tid; k < K_CODES; k += NW * 64) {
        const float* row = emb + (size_t)k * D_DIM;
        float r[8];
        #pragma unroll
        for (int j = 0; j < 8; ++j) r[j] = fmul_x(row[j], row[j]);
        for (int i = 8; i < D_DIM; i += 8) {
            #pragma unroll
            for (int j = 0; j < 8; ++j)
                r[j] = fadd_x(r[j], fmul_x(row[i + j], row[i + j]));
        }
        const float s01 = fadd_x(r[0], r[1]), s23 = fadd_x(r[2], r[3]);
        const float s45 = fadd_x(r[4], r[5]), s67 = fadd_x(r[6], r[7]);
        snorm[k] = fadd_x(fadd_x(s01, s23), fadd_x(s45, s67));
    }
    __syncthreads();                            // z + snorm visible

    // ---- build A-frags: wave ky owns px rows [ky*16, ky*16+16) ----
    const int lm = px & 15;                     // 16-index (A row / B col)
    const int lg = px >> 4;                     // d-slice group 0..3
    const int pxbase = ky * 16;

    s16x8 afr[4];
    #pragma unroll
    for (int dt = 0; dt < 4; ++dt) {
        const float* zr = &s_zT[pxbase + lm][dt * 32 + lg * 8];
        const f32x4 z0 = *(const f32x4*)zr;
        const f32x4 z1 = *(const f32x4*)(zr + 4);
        s16x8 a;
        a[0] = (short)f2bf(z0[0]); a[1] = (short)f2bf(z0[1]);
        a[2] = (short)f2bf(z0[2]); a[3] = (short)f2bf(z0[3]);
        a[4] = (short)f2bf(z1[0]); a[5] = (short)f2bf(z1[1]);
        a[6] = (short)f2bf(z1[2]); a[7] = (short)f2bf(z1[3]);
        afr[dt] = a;
    }

    // ================= pass 1: coarse min per pixel =================
    float m0 = __builtin_inff(), m1 = m0, m2 = m0, m3 = m0;
    {
        int buf = 0;
        stage_tiles(emb, e_s[0], 0, tid);
        __syncthreads();                        // round-0 frags staged
        #pragma unroll 1
        for (int r = 0; r < ROUNDS; ++r) {
            if (r + 1 < ROUNDS)
                stage_tiles(emb, e_s[buf ^ 1], (r + 1) * TPR, tid);
            #pragma unroll
            for (int tt = 0; tt < TPR; ++tt) {
                const unsigned short* fb = e_s[buf] + (size_t)tt * 2048 + (size_t)px * 8;
                const s16x8 c0 = *(const s16x8*)(fb);
                const s16x8 c1 = *(const s16x8*)(fb + 512);
                const s16x8 c2 = *(const s16x8*)(fb + 1024);
                const s16x8 c3 = *(const s16x8*)(fb + 1536);
                f32x4 a0 = {0.f, 0.f, 0.f, 0.f};
                f32x4 a1 = {0.f, 0.f, 0.f, 0.f};
                a0 = __builtin_amdgcn_mfma_f32_16x16x32_bf16(afr[0], c0, a0, 0, 0, 0);
                a0 = __builtin_amdgcn_mfma_f32_16x16x32_bf16(afr[1], c1, a0, 0, 0, 0);
                a1 = __builtin_amdgcn_mfma_f32_16x16x32_bf16(afr[2], c2, a1, 0, 0, 0);
                a1 = __builtin_amdgcn_mfma_f32_16x16x32_bf16(afr[3], c3, a1, 0, 0, 0);
                const float sn = snorm[(r * TPR + tt) * 16 + lm];
                m0 = fminf(m0, fmaf(-2.f, a0[0] + a1[0], sn));
                m1 = fminf(m1, fmaf(-2.f, a0[1] + a1[1], sn));
                m2 = fminf(m2, fmaf(-2.f, a0[2] + a1[2], sn));
                m3 = fminf(m3, fmaf(-2.f, a0[3] + a1[3], sn));
            }
            __syncthreads();                    // next buf staged; this buf free
            buf ^= 1;
        }
    }
    // reduce across the 16 lanes sharing each px row (xor masks stay in-group)
    float gm[4] = {m0, m1, m2, m3};
    #pragma unroll
    for (int r = 0; r < 4; ++r) {
        #pragma unroll
        for (int mask = 1; mask < 16; mask <<= 1)
            gm[r] = fminf(gm[r], __shfl_xor(gm[r], mask, 64));
    }

    // ====== pass 2: bitwise-identical recompute, collect within TH ======
    {
        int buf = 0;
        stage_tiles(emb, e_s[0], 0, tid);       // e_s[0] free after pass-1's last barrier
        __syncthreads();
        #pragma unroll 1
        for (int r = 0; r < ROUNDS; ++r) {
            if (r + 1 < ROUNDS)
                stage_tiles(emb, e_s[buf ^ 1], (r + 1) * TPR, tid);
            #pragma unroll
            for (int tt = 0; tt < TPR; ++tt) {
                const unsigned short* fb = e_s[buf] + (size_t)tt * 2048 + (size_t)px * 8;
                const s16x8 c0 = *(const s16x8*)(fb);
                const s16x8 c1 = *(const s16x8*)(fb + 512);
                const s16x8 c2 = *(const s16x8*)(fb + 1024);
                const s16x8 c3 = *(const s16x8*)(fb + 1536);
                f32x4 a0 = {0.f, 0.f, 0.f, 0.f};
                f32x4 a1 = {0.f, 0.f, 0.f, 0.f};
                a0 = __builtin_amdgcn_mfma_f32_16x16x32_bf16(afr[0], c0, a0, 0, 0, 0);
                a0 = __builtin_amdgcn_mfma_f32_16x16x32_bf16(afr[1], c1, a0, 0, 0, 0);
                a1 = __builtin_amdgcn_mfma_f32_16x16x32_bf16(afr[2], c2, a1, 0, 0, 0);
                a1 = __builtin_amdgcn_mfma_f32_16x16x32_bf16(afr[3], c3, a1, 0, 0, 0);
                const int code = (r * TPR + tt) * 16 + lm;
                const float sn = snorm[code];
                #pragma unroll
                for (int q = 0; q < 4; ++q) {
                    const float t = fmaf(-2.f, a0[q] + a1[q], sn);
                    if (t <= gm[q] + TH) {
                        const int prow = pxbase + lg * 4 + q;   // C/D row -> pixel
                        const int slot = atomicAdd(&s_cnt[prow], 1);
                        if (slot < CAP) s_ck[prow][slot] = code;
                    }
                }
            }
            __syncthreads();
            buf ^= 1;
        }
    }

    // ---- exact refinement (waves 0-1): ref chains verbatim ----
    if (ky < 2) {
        const int p = ky * 64 + px;
        // A: sequential over d (value cancels per-pixel; chain kept honest).
        const float z0 = s_zT[p][0];
        float A32 = fmul_x(z0, z0);
        for (int d = 1; d < D_DIM; ++d) {
            const float zd = s_zT[p][d];
            A32 = fadd_x(A32, fmul_x(zd, zd));
        }

        float bestq = __builtin_inff(); int bestk = 0x7fffffff;
        const int cnt = s_cnt[p];
        if (cnt <= CAP) {
            for (int i = 0; i < cnt; ++i) {
                const int kc = s_ck[p][i];
                const float* e = emb + (size_t)kc * D_DIM;
                float B32 = 0.f;
                for (int d = 0; d < D_DIM; ++d)
                    B32 = ffma_x(s_zT[p][d], e[d], B32);
                const float twoB = fmul_x(2.0f, B32);          // exact
                const float q    = fadd_x(fsub_x(A32, twoB), snorm[kc]);
                if (q < bestq || (q == bestq && kc < bestk)) { bestq = q; bestk = kc; }
            }
        } else {
            // worklist overflow (P ~ 1e-10/px): exact full scan, still correct
            for (int kc = 0; kc < K_CODES; ++kc) {
                const float* e = emb + (size_t)kc * D_DIM;
                float B32 = 0.f;
                for (int d = 0; d < D_DIM; ++d)
                    B32 = ffma_x(s_zT[p][d], e[d], B32);
                const float twoB = fmul_x(2.0f, B32);
                const float q    = fadd_x(fsub_x(A32, twoB), snorm[kc]);
                if (q < bestq || (q == bestq && kc < bestk)) { bestq = q; bestk = kc; }
            }
        }
        s_kwin[p] = bestk;
    }
    __syncthreads();

    // ---- epilogue: out0 = fl(fl(e-z)+z) (pinned), out1 = e ----
    const int p  = tid & 127;                   // pixel
    const int dg = tid >> 7;                    // d-quarter 0..3
    const int kwin = s_kwin[p];
    const float* er = emb + (size_t)kwin * D_DIM + dg * 32;
    float* o0 = out + (size_t)b * (D_DIM * HW_SZ) + hw0 + p;
    float* o1 = o0 + OUT_OFF;
    #pragma unroll
    for (int i = 0; i < 8; ++i) {
        const f32x4 e4 = *(const f32x4*)(er + i * 4);
        #pragma unroll
        for (int j = 0; j < 4; ++j) {
            const int d = dg * 32 + i * 4 + j;
            const float zv = s_zT[p][d];
            o0[(size_t)d * HW_SZ] = fadd_x(fsub_x(e4[j], zv), zv);
            o1[(size_t)d * HW_SZ] = e4[j];
        }
    }
}

extern "C" void kernel_launch(void* const* d_in, const int* in_sizes, int n_in,
                              void* d_out, int out_size, void* d_ws, size_t ws_size,
                              hipStream_t stream)
{
    const float* z_e = (const float*)d_in[0];
    const float* emb = (const float*)d_in[1];
    float* out = (float*)d_out;
    (void)in_sizes; (void)n_in; (void)out_size; (void)d_ws; (void)ws_size;

    vq_fused<<<dim3(N_PIX / PXB), dim3(64, NW), 0, stream>>>(z_e, emb, out);
}

// Round 8
// 653.076 us; speedup vs baseline: 7.3064x; 7.3064x over previous
//
#include <hip/hip_runtime.h>
#include <cmath>

// VQ-VAE quantization forward: B=64, K=1024, D=128, H=W=32.
// Ref model (6 rounds of absmax triangulation): q_k = fl32(fl32(A - fl32(2*B_k)) + C_k),
// first-index argmin, B = single-accumulator SEQUENTIAL FMA over d.
// A = sum(z*z,-1) sequential; C = sum(emb*emb,-1) pairwise-8.
// out0 = fl(fl(e-z)+z); out1 = e. Exact chains pinned with empty-asm barriers.
//
// R8 == R7 resubmitted verbatim: the R7 bench died at the container level
// (acquire/run infra failure) with no counters; kernel audit found no hang
// path (uniform barriers, correct dbuf pipeline, aligned vec accesses,
// always-valid kwin). Keeping the source identical preserves the experiment.
//
// R7 rationale: R4/R5/R6 proved the coarse feed was NEVER the bottleneck
// (3 different feeds, identical 4.5-4.8ms, identical conflict counts,
// occupancy 3.6% = CUs empty 86% of the time vs R3's healthy 24%). The R4+
// two-pass + LDS-atomic worklist + fallback tail starves dispatch. R7 = R3's
// PROVEN shape (single pass, in-register selection, pinned-chain refinement,
// same 104,960B LDS footprint) with only the coarse scoring swapped to MFMA
// (R6's verified staging + fragment maps):
//  * single coarse pass; each lane keeps a 4-deep top list per pixel-row for
//    its code COLUMN (eviction-safe: needs >=4 same-column codes within
//    2*err=1.6e-3 of q*; P ~ 1e-3 worst-bound, ~1e-6 realistic).
//  * gmin via 16-lane shfl; lanes exact-refine their own qualifying
//    candidates (<= gmin + MARGIN, expected ~1.5/px); packed (q,k) u64
//    shfl-min gives first-index argmin. No atomics, no 2nd pass, no fallback.
//  * MARGIN=2e-3 >= 2*err_coarse worst bound (|2 sum z*de| + |2 sum e*dz|
//    <= ~8e-4; realistic 3sigma ~3e-4).
// Verbatim from validated kernels: fragment bijection (l&15=code, l>>4=
// d-slice), C/D map col=lane&15(code) row=(lane>>4)*4+reg(px), f2bf bits,
// snorm pairwise-8 / A / B / epilogue pinned chains, first-index tie-break.

#define D_DIM   128
#define K_CODES 1024
#define HW_SZ   1024
#define N_PIX   65536
#define OUT_OFF ((size_t)N_PIX * D_DIM)

#define PXB     128                     // pixels per block
#define NW      8                       // waves per block
#define NTILE   (K_CODES / 16)          // 64 code-tiles
#define TPR     4                       // tiles staged per round
#define ROUNDS  (NTILE / TPR)           // 16
#define ZLD     132                     // padded z row (floats)
#define NK      4                       // top-list depth per column per px-row
#define MARGIN  2.0e-3f                 // coarse->exact window

typedef float  f32x4 __attribute__((ext_vector_type(4)));
typedef short  s16x8 __attribute__((ext_vector_type(8)));
typedef unsigned short u16x8 __attribute__((ext_vector_type(8)));

// --- compiler-proof fp32 ops: result pinned in a VGPR via empty asm ---
__device__ __forceinline__ float fmul_x(float a, float b) {
    float r = a * b; asm volatile("" : "+v"(r)); return r;
}
__device__ __forceinline__ float fadd_x(float a, float b) {
    float r = a + b; asm volatile("" : "+v"(r)); return r;
}
__device__ __forceinline__ float fsub_x(float a, float b) {
    float r = a - b; asm volatile("" : "+v"(r)); return r;
}
__device__ __forceinline__ float ffma_x(float a, float b, float c) {
    float r = fmaf(a, b, c); asm volatile("" : "+v"(r)); return r;
}

// RNE float -> bf16 bits (inputs are normal floats here)
__device__ __forceinline__ unsigned short f2bf(float f) {
    unsigned u = __float_as_uint(f);
    u += 0x7FFFu + ((u >> 16) & 1u);
    return (unsigned short)(u >> 16);
}

// Stage TPR tiles (Tbase..Tbase+3) into dst in fragment order:
// dst[((tt*4 + dt)*64 + l)*8 + j] = bf16(emb[(Tbase+tt)*16 + (l&15)][dt*32 + ((l>>4)&3)*8 + j])
__device__ __forceinline__ void stage_tiles(
    const float* __restrict__ emb, unsigned short* __restrict__ dst,
    const int Tbase, const int tid)
{
    #pragma unroll
    for (int h = 0; h < 2; ++h) {
        const int f  = h * 512 + tid;        // fragment id 0..1023
        const int tt = f >> 8;               // tile within round
        const int dt = (f >> 6) & 3;         // d-block
        const int l  = f & 63;               // fragment lane
        const int code = (Tbase + tt) * 16 + (l & 15);
        const int d0   = dt * 32 + ((l >> 4) & 3) * 8;
        const float* src = emb + (size_t)code * D_DIM + d0;
        const f32x4 a = *(const f32x4*)(src);
        const f32x4 b = *(const f32x4*)(src + 4);
        u16x8 o;
        o[0] = f2bf(a[0]); o[1] = f2bf(a[1]); o[2] = f2bf(a[2]); o[3] = f2bf(a[3]);
        o[4] = f2bf(b[0]); o[5] = f2bf(b[1]); o[6] = f2bf(b[2]); o[7] = f2bf(b[3]);
        *(u16x8*)(dst + (size_t)f * 8) = o;
    }
}

__global__ __launch_bounds__(512, 2) void vq_fused(
    const float* __restrict__ z_e,
    const float* __restrict__ emb,
    float* __restrict__ out)
{
#pragma clang fp contract(off)
    __shared__ float s_zT[PXB][ZLD];                          // 67584 B fp32 z, [px][d]
    __shared__ alignas(16) unsigned short e_s[2][TPR * 2048]; // 32768 B frag dbuf
    __shared__ float snorm[K_CODES];                          // 4096 B
    __shared__ int   s_kwin[PXB];                             // 512 B
    // total 104,960 B == R3's proven footprint

    const int px  = threadIdx.x;                // lane 0..63
    const int ky  = threadIdx.y;                // wave 0..7
    const int tid = ky * 64 + px;

    const int p0  = blockIdx.x * PXB;
    const int b   = p0 >> 10;
    const int hw0 = p0 & (HW_SZ - 1);
    const float* zbase = z_e + (size_t)b * (D_DIM * HW_SZ) + hw0;

    // ---- z stage: global [d][128 px] -> s_zT[px][d] (transpose) ----
    #pragma unroll
    for (int r = 0; r < 8; ++r) {
        const int idx = r * 512 + tid;          // 0..4095
        const int d   = idx >> 5;               // 0..127
        const int i4  = (idx & 31) * 4;         // pixel group
        const f32x4 v = *(const f32x4*)(zbase + (size_t)d * HW_SZ + i4);
        s_zT[i4 + 0][d] = v[0];
        s_zT[i4 + 1][d] = v[1];
        s_zT[i4 + 2][d] = v[2];
        s_zT[i4 + 3][d] = v[3];
    }

    // ---- C_k = np.sum(emb*emb,-1): pairwise-8 (n=128), chain verbatim ----
    for (int k = tid; k < K_CODES; k += NW * 64) {
        const float* row = emb + (size_t)k * D_DIM;
        float r[8];
        #pragma unroll
        for (int j = 0; j < 8; ++j) r[j] = fmul_x(row[j], row[j]);
        for (int i = 8; i < D_DIM; i += 8) {
            #pragma unroll
            for (int j = 0; j < 8; ++j)
                r[j] = fadd_x(r[j], fmul_x(row[i + j], row[i + j]));
        }
        const float s01 = fadd_x(r[0], r[1]), s23 = fadd_x(r[2], r[3]);
        const float s45 = fadd_x(r[4], r[5]), s67 = fadd_x(r[6], r[7]);
        snorm[k] = fadd_x(fadd_x(s01, s23), fadd_x(s45, s67));
    }

    // ---- round-0 e-frags ----
    stage_tiles(emb, e_s[0], 0, tid);
    __syncthreads();                            // z + snorm + round-0 frags visible

    // ---- build A-frags: wave ky owns px rows [ky*16, ky*16+16) ----
    const int lm = px & 15;                     // 16-index (A row / B col)
    const int lg = px >> 4;                     // d-slice group 0..3
    const int pxbase = ky * 16;

    s16x8 afr[4];
    #pragma unroll
    for (int dt = 0; dt < 4; ++dt) {
        const float* zr = &s_zT[pxbase + lm][dt * 32 + lg * 8];
        const f32x4 z0 = *(const f32x4*)zr;
        const f32x4 z1 = *(const f32x4*)(zr + 4);
        s16x8 a;
        a[0] = (short)f2bf(z0[0]); a[1] = (short)f2bf(z0[1]);
        a[2] = (short)f2bf(z0[2]); a[3] = (short)f2bf(z0[3]);
        a[4] = (short)f2bf(z1[0]); a[5] = (short)f2bf(z1[1]);
        a[6] = (short)f2bf(z1[2]); a[7] = (short)f2bf(z1[3]);
        afr[dt] = a;
    }

    // per-(px-row, column) 4-deep top lists, all indices compile-time constant
    float ct[4][NK]; int ck[4][NK];
    #pragma unroll
    for (int r = 0; r < 4; ++r) {
        #pragma unroll
        for (int s = 0; s < NK; ++s) { ct[r][s] = __builtin_inff(); ck[r][s] = 0; }
    }

    // ====== single coarse pass: MFMA scores + in-register selection ======
    {
        int buf = 0;
        #pragma unroll 1
        for (int rnd = 0; rnd < ROUNDS; ++rnd) {
            if (rnd + 1 < ROUNDS)
                stage_tiles(emb, e_s[buf ^ 1], (rnd + 1) * TPR, tid);
            #pragma unroll
            for (int tl = 0; tl < TPR; ++tl) {
                const unsigned short* fb = e_s[buf] + (size_t)tl * 2048 + (size_t)px * 8;
                const s16x8 c0 = *(const s16x8*)(fb);
                const s16x8 c1 = *(const s16x8*)(fb + 512);
                const s16x8 c2 = *(const s16x8*)(fb + 1024);
                const s16x8 c3 = *(const s16x8*)(fb + 1536);
                f32x4 a0 = {0.f, 0.f, 0.f, 0.f};
                f32x4 a1 = {0.f, 0.f, 0.f, 0.f};
                a0 = __builtin_amdgcn_mfma_f32_16x16x32_bf16(afr[0], c0, a0, 0, 0, 0);
                a0 = __builtin_amdgcn_mfma_f32_16x16x32_bf16(afr[1], c1, a0, 0, 0, 0);
                a1 = __builtin_amdgcn_mfma_f32_16x16x32_bf16(afr[2], c2, a1, 0, 0, 0);
                a1 = __builtin_amdgcn_mfma_f32_16x16x32_bf16(afr[3], c3, a1, 0, 0, 0);
                const int code = (rnd * TPR + tl) * 16 + lm;
                const float sn = snorm[code];
                #pragma unroll
                for (int r = 0; r < 4; ++r) {
                    const float t = fmaf(-2.f, a0[r] + a1[r], sn);
                    if (t < ct[r][3]) {
                        if (t < ct[r][1]) {
                            ct[r][3] = ct[r][2]; ck[r][3] = ck[r][2];
                            ct[r][2] = ct[r][1]; ck[r][2] = ck[r][1];
                            if (t < ct[r][0]) {
                                ct[r][1] = ct[r][0]; ck[r][1] = ck[r][0];
                                ct[r][0] = t; ck[r][0] = code;
                            } else { ct[r][1] = t; ck[r][1] = code; }
                        } else {
                            if (t < ct[r][2]) {
                                ct[r][3] = ct[r][2]; ck[r][3] = ck[r][2];
                                ct[r][2] = t; ck[r][2] = code;
                            } else { ct[r][3] = t; ck[r][3] = code; }
                        }
                    }
                }
            }
            __syncthreads();                    // next buf staged; this buf free
            buf ^= 1;
        }
    }

    // ---- gmin per pixel row via 16-lane shfl (masks stay in-group) ----
    float gmin[4];
    #pragma unroll
    for (int r = 0; r < 4; ++r) {
        gmin[r] = ct[r][0];
        #pragma unroll
        for (int mask = 1; mask < 16; mask <<= 1)
            gmin[r] = fminf(gmin[r], __shfl_xor(gmin[r], mask, 64));
    }

    // ---- per-lane exact refinement of qualifying candidates + u64 combine ----
    #pragma unroll 1
    for (int r = 0; r < 4; ++r) {
        const int prow = pxbase + lg * 4 + r;
        const float thr = gmin[r] + MARGIN;
        unsigned long long pack = ~0ULL;
        bool any = false;
        #pragma unroll
        for (int s = 0; s < NK; ++s) any = any || (ct[r][s] <= thr);
        if (any) {
            // A: sequential over d (chain kept honest; value cancels per-pixel).
            const float z0 = s_zT[prow][0];
            float A32 = fmul_x(z0, z0);
            for (int d = 1; d < D_DIM; ++d) {
                const float zd = s_zT[prow][d];
                A32 = fadd_x(A32, fmul_x(zd, zd));
            }
            #pragma unroll 1
            for (int s = 0; s < NK; ++s) {
                if (ct[r][s] <= thr) {
                    const int kc = ck[r][s];
                    const float* e = emb + (size_t)kc * D_DIM;
                    // B: GEMM-style single-accumulator SEQUENTIAL FMA over d.
                    float B32 = 0.f;
                    for (int d = 0; d < D_DIM; ++d)
                        B32 = ffma_x(s_zT[prow][d], e[d], B32);
                    const float twoB = fmul_x(2.0f, B32);      // exact
                    const float q    = fadd_x(fsub_x(A32, twoB), snorm[kc]);
                    // q = ||z-e||^2 ~ ||z||^2 > 0: positive-float uint order OK.
                    const unsigned long long p =
                        ((unsigned long long)__float_as_uint(q) << 32) |
                        (unsigned)kc;          // low bits = k: first-index tie-break
                    pack = (p < pack) ? p : pack;
                }
            }
        }
        // convergent 16-lane min-combine of packed (q,k)
        #pragma unroll
        for (int mask = 1; mask < 16; mask <<= 1) {
            const unsigned long long o = __shfl_xor(pack, mask, 64);
            pack = (o < pack) ? o : pack;
        }
        if (lm == 0) s_kwin[prow] = (int)(pack & 0xffffffffu);
    }
    __syncthreads();

    // ---- epilogue: out0 = fl(fl(e-z)+z) (pinned), out1 = e ----
    const int p  = tid & 127;                   // pixel
    const int dg = tid >> 7;                    // d-quarter 0..3
    const int kwin = s_kwin[p];
    const float* er = emb + (size_t)kwin * D_DIM + dg * 32;
    float* o0 = out + (size_t)b * (D_DIM * HW_SZ) + hw0 + p;
    float* o1 = o0 + OUT_OFF;
    #pragma unroll
    for (int i = 0; i < 8; ++i) {
        const f32x4 e4 = *(const f32x4*)(er + i * 4);
        #pragma unroll
        for (int j = 0; j < 4; ++j) {
            const int d = dg * 32 + i * 4 + j;
            const float zv = s_zT[p][d];
            o0[(size_t)d * HW_SZ] = fadd_x(fsub_x(e4[j], zv), zv);
            o1[(size_t)d * HW_SZ] = e4[j];
        }
    }
}

extern "C" void kernel_launch(void* const* d_in, const int* in_sizes, int n_in,
                              void* d_out, int out_size, void* d_ws, size_t ws_size,
                              hipStream_t stream)
{
    const float* z_e = (const float*)d_in[0];
    const float* emb = (const float*)d_in[1];
    float* out = (float*)d_out;
    (void)in_sizes; (void)n_in; (void)out_size; (void)d_ws; (void)ws_size;

    vq_fused<<<dim3(N_PIX / PXB), dim3(64, NW), 0, stream>>>(z_e, emb, out);
}